// Round 1
// baseline (40.453 us; speedup 1.0000x reference)
//
#include <hip/hip_runtime.h>
#include <math.h>

// ---------------- complex helpers (fp32) ----------------
struct C2 { float r, i; };
__device__ inline C2 cmul(C2 a, C2 b) {
    return { a.r * b.r - a.i * b.i, a.r * b.i + a.i * b.r };
}
__device__ inline C2 cadd(C2 a, C2 b) { return { a.r + b.r, a.i + b.i }; }
__device__ inline C2 cconj(C2 a) { return { a.r, -a.i }; }

__device__ inline void mat4mul(const C2 A[4][4], const C2 B[4][4], C2 O[4][4]) {
    for (int i = 0; i < 4; ++i)
        for (int j = 0; j < 4; ++j) {
            C2 acc = {0.f, 0.f};
            for (int k = 0; k < 4; ++k) acc = cadd(acc, cmul(A[i][k], B[k][j]));
            O[i][j] = acc;
        }
}

__device__ inline void kron2(const C2 a[2][2], const C2 b[2][2], C2 o[4][4]) {
    for (int i0 = 0; i0 < 2; ++i0)
        for (int i1 = 0; i1 < 2; ++i1)
            for (int j0 = 0; j0 < 2; ++j0)
                for (int j1 = 0; j1 < 2; ++j1)
                    o[2 * i0 + i1][2 * j0 + j1] = cmul(a[i0][j0], b[i1][j1]);
}

// ---------------- prelude: params -> 9 bilinear coefficients ----------------
// logit(x0,x1) = u0^T K u1 with u0=[1,cos x0,sin x0], u1=[1,cos x1,sin x1].
// K folded with W[0][0] and b[0] so main kernel outputs the final value.
__global__ void fraud_prelude(const float* __restrict__ params, int n_layers,
                              const float* __restrict__ W, const float* __restrict__ bias,
                              float* __restrict__ K) {
    if (threadIdx.x != 0 || blockIdx.x != 0) return;

    C2 U[4][4];
    for (int i = 0; i < 4; ++i)
        for (int j = 0; j < 4; ++j)
            U[i][j] = { (i == j) ? 1.f : 0.f, 0.f };

    const float is2 = 0.70710678118654752f;
    // H 2x2 (real)
    C2 Hm[2][2] = { { {is2,0.f},{is2,0.f} }, { {is2,0.f},{-is2,0.f} } };
    // CNOT (wire0 control): rows 2,3 swapped identity
    C2 CN[4][4];
    for (int i = 0; i < 4; ++i)
        for (int j = 0; j < 4; ++j) CN[i][j] = {0.f, 0.f};
    CN[0][0] = {1.f,0.f}; CN[1][1] = {1.f,0.f}; CN[2][3] = {1.f,0.f}; CN[3][2] = {1.f,0.f};

    for (int l = 0; l < n_layers; ++l) {
        float p[14];
        for (int j = 0; j < 14; ++j) {
            float v = params[l * 14 + j];
            float lim = (j < 12) ? 5.0f : 1.0f;
            p[j] = fminf(fmaxf(v, -lim), lim);
        }

        // PhaseShift: diag(1, e^{ip})
        C2 PH0[2][2] = { { {1.f,0.f},{0.f,0.f} }, { {0.f,0.f},{cosf(p[2]), sinf(p[2])} } };
        C2 PH1[2][2] = { { {1.f,0.f},{0.f,0.f} }, { {0.f,0.f},{cosf(p[3]), sinf(p[3])} } };

        // RZ(t) = diag(e^{-it/2}, e^{it/2})
        float t0 = p[4] + p[6], t1 = p[5] + p[7];
        C2 RZ0[2][2] = { { {cosf(0.5f*t0), -sinf(0.5f*t0)}, {0.f,0.f} },
                         { {0.f,0.f}, {cosf(0.5f*t0),  sinf(0.5f*t0)} } };
        C2 RZ1[2][2] = { { {cosf(0.5f*t1), -sinf(0.5f*t1)}, {0.f,0.f} },
                         { {0.f,0.f}, {cosf(0.5f*t1),  sinf(0.5f*t1)} } };

        // D_q = RY(phi_d) @ RZ(r):  [[c*em, -s*ep],[s*em, c*ep]]
        float c0 = cosf(0.5f * p[10]), s0 = sinf(0.5f * p[10]);
        C2 em0 = { cosf(0.5f * p[8]), -sinf(0.5f * p[8]) };
        C2 ep0 = { em0.r, -em0.i };
        C2 D0m[2][2] = { { {c0*em0.r, c0*em0.i}, {-s0*ep0.r, -s0*ep0.i} },
                         { {s0*em0.r, s0*em0.i}, { c0*ep0.r,  c0*ep0.i} } };
        float c1 = cosf(0.5f * p[11]), s1 = sinf(0.5f * p[11]);
        C2 em1 = { cosf(0.5f * p[9]), -sinf(0.5f * p[9]) };
        C2 ep1 = { em1.r, -em1.i };
        C2 D1m[2][2] = { { {c1*em1.r, c1*em1.i}, {-s1*ep1.r, -s1*ep1.i} },
                         { {s1*em1.r, s1*em1.i}, { c1*ep1.r,  c1*ep1.i} } };

        C2 P4[4][4], S4[4][4], D4[4][4], HH4[4][4];
        kron2(PH0, PH1, P4);
        kron2(RZ0, RZ1, S4);
        kron2(D0m, D1m, D4);
        kron2(Hm, Hm, HH4);

        C2 T1[4][4], T2[4][4], T3[4][4], T4[4][4];
        mat4mul(HH4, CN, T1);   // HH @ CNOT
        mat4mul(P4, T1, T2);    // P @ ...
        mat4mul(S4, T2, T3);    // S @ ...
        mat4mul(D4, T3, T4);    // D @ ...
        // CP = diag(1,1,1, e^{i(p12+p13)}) : scale row 3
        C2 cp = { cosf(p[12] + p[13]), sinf(p[12] + p[13]) };
        for (int j = 0; j < 4; ++j) T4[3][j] = cmul(cp, T4[3][j]);

        C2 Un[4][4];
        mat4mul(T4, U, Un);     // U = layer @ U
        for (int i = 0; i < 4; ++i)
            for (int j = 0; j < 4; ++j) U[i][j] = Un[i][j];
    }

    // M = U^dag (Z kron I) U, Hermitian
    const float z[4] = { 1.f, 1.f, -1.f, -1.f };
    C2 M[4][4];
    for (int i = 0; i < 4; ++i)
        for (int j = 0; j < 4; ++j) {
            C2 acc = {0.f, 0.f};
            for (int k = 0; k < 4; ++k) {
                C2 t = cmul(cconj(U[k][i]), U[k][j]);
                acc.r += z[k] * t.r;
                acc.i += z[k] * t.i;
            }
            M[i][j] = acc;
        }

    // A = Re(Dp^dag M Dp), Dp = diag(1, -i, -i, -1)
    const C2 dph[4] = { {1.f,0.f}, {0.f,-1.f}, {0.f,-1.f}, {-1.f,0.f} };
    float A[4][4];
    for (int i = 0; i < 4; ++i)
        for (int j = 0; j < 4; ++j) {
            C2 t = cmul(cconj(dph[i]), cmul(M[i][j], dph[j]));
            A[i][j] = t.r;
        }

    // bilinear coefficients over (1, C0, S0) x (1, C1, S1)
    float k00 = 0.25f * (A[0][0] + A[1][1] + A[2][2] + A[3][3]);
    float k01 = 0.25f * (A[0][0] - A[1][1] + A[2][2] - A[3][3]);
    float k02 = 0.5f  * (A[0][1] + A[2][3]);
    float k10 = 0.25f * (A[0][0] + A[1][1] - A[2][2] - A[3][3]);
    float k11 = 0.25f * (A[0][0] - A[1][1] - A[2][2] + A[3][3]);
    float k12 = 0.5f  * (A[0][1] - A[2][3]);
    float k20 = 0.5f  * (A[0][2] + A[1][3]);
    float k21 = 0.5f  * (A[0][2] - A[1][3]);
    float k22 = 0.5f  * (A[0][3] + A[1][2]);

    float w = W[0], bb = bias[0];
    K[0] = k00 * w + bb;
    K[1] = k01 * w;
    K[2] = k02 * w;
    K[3] = k10 * w;
    K[4] = k11 * w;
    K[5] = k12 * w;
    K[6] = k20 * w;
    K[7] = k21 * w;
    K[8] = k22 * w;
}

// ---------------- main: streaming evaluation ----------------
__device__ inline float eval_sample(float x0, float x1,
                                    float k00, float k01, float k02,
                                    float k10, float k11, float k12,
                                    float k20, float k21, float k22) {
    float s0, c0, s1, c1;
    __sincosf(x0, &s0, &c0);
    __sincosf(x1, &s1, &c1);
    float e0 = fmaf(s1, k02, fmaf(c1, k01, k00));
    float e1 = fmaf(s1, k12, fmaf(c1, k11, k10));
    float e2 = fmaf(s1, k22, fmaf(c1, k21, k20));
    return fmaf(s0, e2, fmaf(c0, e1, e0));
}

__global__ __launch_bounds__(256) void fraud_main(const float4* __restrict__ x,
                                                  const float* __restrict__ K,
                                                  float4* __restrict__ out,
                                                  int nquads) {
    int t = blockIdx.x * 256 + threadIdx.x;
    if (t >= nquads) return;

    float k00 = K[0], k01 = K[1], k02 = K[2];
    float k10 = K[3], k11 = K[4], k12 = K[5];
    float k20 = K[6], k21 = K[7], k22 = K[8];

    float4 xa = x[2 * t];
    float4 xb = x[2 * t + 1];

    float4 o;
    o.x = eval_sample(xa.x, xa.y, k00, k01, k02, k10, k11, k12, k20, k21, k22);
    o.y = eval_sample(xa.z, xa.w, k00, k01, k02, k10, k11, k12, k20, k21, k22);
    o.z = eval_sample(xb.x, xb.y, k00, k01, k02, k10, k11, k12, k20, k21, k22);
    o.w = eval_sample(xb.z, xb.w, k00, k01, k02, k10, k11, k12, k20, k21, k22);
    out[t] = o;
}

extern "C" void kernel_launch(void* const* d_in, const int* in_sizes, int n_in,
                              void* d_out, int out_size, void* d_ws, size_t ws_size,
                              hipStream_t stream) {
    const float* x      = (const float*)d_in[0];
    const float* params = (const float*)d_in[1];
    const float* W      = (const float*)d_in[2];
    const float* b      = (const float*)d_in[3];
    float* out = (float*)d_out;
    float* Kws = (float*)d_ws;

    int n_layers = in_sizes[1] / 14;
    int B = out_size;              // n_classes == 1

    fraud_prelude<<<1, 1, 0, stream>>>(params, n_layers, W, b, Kws);

    int nq = B / 4;                // B divisible by 4 (B = 4194304)
    int blocks = (nq + 255) / 256;
    fraud_main<<<blocks, 256, 0, stream>>>((const float4*)x, Kws, (float4*)out, nq);
}

// Round 2
// 17.693 us; speedup vs baseline: 2.2864x; 2.2864x over previous
//
#include <hip/hip_runtime.h>
#include <math.h>

// ============================================================================
// Prelude: params (3x14) -> 9 bilinear coefficients K, wave-parallel.
//
// logit(x0,x1) = u0^T K u1,  u0=[1,cos x0,sin x0], u1=[1,cos x1,sin x1],
// K folded with W[0] and b[0].
//
// Layer unitary = CP * D * S * P * HH * CNOT. CP,S,P diagonal; HH*CNOT is a
// constant real +-0.5 matrix (HH with cols 2,3 swapped). So per layer only two
// true 4x4 complex matmuls: L = D @ (e^{i theta_i} * HHC) (+ CP row-3 scale),
// then U = L @ U. 16 lanes own one (i,j) element each; matmuls via LDS.
// ============================================================================

// D_q = RY(phid) @ RZ(r) element [a][b]
__device__ inline void delem(float r, float phid, int a, int b,
                             float& outr, float& outi) {
    float sn, cs; __sincosf(0.5f * r, &sn, &cs);      // em = (cs, -sn), ep = (cs, +sn)
    float sd, cd; __sincosf(0.5f * phid, &sd, &cd);
    float f = (a == b) ? cd : ((a == 1) ? sd : -sd);  // [[c, -s],[s, c]] magnitude
    outr = f * cs;
    outi = f * ((b == 1) ? sn : -sn);                 // col 0 -> em, col 1 -> ep
}

__global__ __launch_bounds__(64) void fraud_prelude(
        const float* __restrict__ params, int n_layers,
        const float* __restrict__ W, const float* __restrict__ bias,
        float* __restrict__ K) {
    __shared__ float Er[16], Ei[16], Dr[16], Di[16];
    __shared__ float Lr[16], Li[16], Ur_[16], Ui_[16], Am[16];

    const int t = threadIdx.x;
    const int i = t >> 2, j = t & 3;
    const bool act = (t < 16);
    const int i0 = i >> 1, i1 = i & 1;
    const int j0 = j >> 1, j1 = j & 1;

    if (act) { Ur_[t] = (i == j) ? 1.f : 0.f; Ui_[t] = 0.f; }
    __syncthreads();

    for (int l = 0; l < n_layers; ++l) {
        float p[14];
        float cp_ang = 0.f;
        if (act) {
            #pragma unroll
            for (int q = 0; q < 14; ++q) {
                float v = params[l * 14 + q];
                float lim = (q < 12) ? 5.0f : 1.0f;
                p[q] = fminf(fmaxf(v, -lim), lim);
            }
            cp_ang = p[12] + p[13];

            // E[i][j] = e^{i theta_i} * HHC[i][j]
            // HHC[i][j] = HH[i][sig(j)], sig swaps cols 2,3; HH[i][j] = 0.5*(-1)^popc(i&j)
            int sj = j ^ (j >> 1);
            float hh = (__popc(i & sj) & 1) ? -0.5f : 0.5f;
            float t0 = p[4] + p[6], t1 = p[5] + p[7];
            float th = p[2] * (float)i0 + p[3] * (float)i1
                     + 0.5f * t0 * (float)(2 * i0 - 1)
                     + 0.5f * t1 * (float)(2 * i1 - 1);
            float sth, cth; __sincosf(th, &sth, &cth);
            Er[t] = hh * cth; Ei[t] = hh * sth;

            // D4[i][j] = D0[i0][j0] * D1[i1][j1]
            float ar, ai, br, bi;
            delem(p[8],  p[10], i0, j0, ar, ai);
            delem(p[9],  p[11], i1, j1, br, bi);
            Dr[t] = ar * br - ai * bi;
            Di[t] = ar * bi + ai * br;
        }
        __syncthreads();

        // L = D4 @ E, then CP scales row 3
        if (act) {
            float lr = 0.f, li = 0.f;
            #pragma unroll
            for (int k = 0; k < 4; ++k) {
                float ar = Dr[4 * i + k], ai = Di[4 * i + k];
                float br = Er[4 * k + j], bi = Ei[4 * k + j];
                lr += ar * br - ai * bi;
                li += ar * bi + ai * br;
            }
            if (i == 3) {
                float cpi, cpr; __sincosf(cp_ang, &cpi, &cpr);
                float nr = lr * cpr - li * cpi;
                float ni = lr * cpi + li * cpr;
                lr = nr; li = ni;
            }
            Lr[t] = lr; Li[t] = li;
        }
        __syncthreads();

        // newU = L @ U
        float nur = 0.f, nui = 0.f;
        if (act) {
            #pragma unroll
            for (int k = 0; k < 4; ++k) {
                float ar = Lr[4 * i + k], ai = Li[4 * i + k];
                float br = Ur_[4 * k + j], bi = Ui_[4 * k + j];
                nur += ar * br - ai * bi;
                nui += ar * bi + ai * br;
            }
        }
        __syncthreads();                 // all reads of old U complete
        if (act) { Ur_[t] = nur; Ui_[t] = nui; }
        __syncthreads();
    }

    // M = U^dag (Z kron I) U; A = Re(conj(dph_i) * M * dph_j), dph = (1,-i,-i,-1)
    if (act) {
        float mr = 0.f, mi = 0.f;
        #pragma unroll
        for (int k = 0; k < 4; ++k) {
            float z = (k < 2) ? 1.f : -1.f;
            float u1r = Ur_[4 * k + i], u1i = -Ui_[4 * k + i];   // conj(U[k][i])
            float u2r = Ur_[4 * k + j], u2i =  Ui_[4 * k + j];
            mr += z * (u1r * u2r - u1i * u2i);
            mi += z * (u1r * u2i + u1i * u2r);
        }
        float dri = (i == 0) ? 1.f : ((i == 3) ? -1.f : 0.f);
        float dii = (i == 0 || i == 3) ? 0.f : -1.f;
        float drj = (j == 0) ? 1.f : ((j == 3) ? -1.f : 0.f);
        float dij = (j == 0 || j == 3) ? 0.f : -1.f;
        float fr = dri * drj + dii * dij;        // conj(dph_i) * dph_j
        float fi = dri * dij - dii * drj;
        Am[t] = mr * fr - mi * fi;
    }
    __syncthreads();

    if (t == 0) {
        float A00 = Am[0],  A01 = Am[1],  A02 = Am[2],  A03 = Am[3];
        float A11 = Am[5],  A12 = Am[6],  A13 = Am[7];
        float A22 = Am[10], A23 = Am[11], A33 = Am[15];

        float k00 = 0.25f * (A00 + A11 + A22 + A33);
        float k01 = 0.25f * (A00 - A11 + A22 - A33);
        float k02 = 0.5f  * (A01 + A23);
        float k10 = 0.25f * (A00 + A11 - A22 - A33);
        float k11 = 0.25f * (A00 - A11 - A22 + A33);
        float k12 = 0.5f  * (A01 - A23);
        float k20 = 0.5f  * (A02 + A13);
        float k21 = 0.5f  * (A02 - A13);
        float k22 = 0.5f  * (A03 + A12);

        float w = W[0], bb = bias[0];
        K[0] = k00 * w + bb;
        K[1] = k01 * w;  K[2] = k02 * w;
        K[3] = k10 * w;  K[4] = k11 * w;  K[5] = k12 * w;
        K[6] = k20 * w;  K[7] = k21 * w;  K[8] = k22 * w;
    }
}

// ============================================================================
// Main: streaming evaluation (memory-bound: 32 MB in + 16 MB out)
// ============================================================================
__device__ inline float eval_sample(float x0, float x1,
                                    float k00, float k01, float k02,
                                    float k10, float k11, float k12,
                                    float k20, float k21, float k22) {
    float s0, c0, s1, c1;
    __sincosf(x0, &s0, &c0);
    __sincosf(x1, &s1, &c1);
    float e0 = fmaf(s1, k02, fmaf(c1, k01, k00));
    float e1 = fmaf(s1, k12, fmaf(c1, k11, k10));
    float e2 = fmaf(s1, k22, fmaf(c1, k21, k20));
    return fmaf(s0, e2, fmaf(c0, e1, e0));
}

__global__ __launch_bounds__(256) void fraud_main(const float4* __restrict__ x,
                                                  const float* __restrict__ K,
                                                  float4* __restrict__ out,
                                                  int nquads) {
    int t = blockIdx.x * 256 + threadIdx.x;
    if (t >= nquads) return;

    float k00 = K[0], k01 = K[1], k02 = K[2];
    float k10 = K[3], k11 = K[4], k12 = K[5];
    float k20 = K[6], k21 = K[7], k22 = K[8];

    float4 xa = x[2 * t];
    float4 xb = x[2 * t + 1];

    float4 o;
    o.x = eval_sample(xa.x, xa.y, k00, k01, k02, k10, k11, k12, k20, k21, k22);
    o.y = eval_sample(xa.z, xa.w, k00, k01, k02, k10, k11, k12, k20, k21, k22);
    o.z = eval_sample(xb.x, xb.y, k00, k01, k02, k10, k11, k12, k20, k21, k22);
    o.w = eval_sample(xb.z, xb.w, k00, k01, k02, k10, k11, k12, k20, k21, k22);
    out[t] = o;
}

extern "C" void kernel_launch(void* const* d_in, const int* in_sizes, int n_in,
                              void* d_out, int out_size, void* d_ws, size_t ws_size,
                              hipStream_t stream) {
    const float* x      = (const float*)d_in[0];
    const float* params = (const float*)d_in[1];
    const float* W      = (const float*)d_in[2];
    const float* b      = (const float*)d_in[3];
    float* out = (float*)d_out;
    float* Kws = (float*)d_ws;

    int n_layers = in_sizes[1] / 14;
    int B = out_size;              // n_classes == 1

    fraud_prelude<<<1, 64, 0, stream>>>(params, n_layers, W, b, Kws);

    int nq = B / 4;                // B = 4194304, divisible by 4
    int blocks = (nq + 255) / 256;
    fraud_main<<<blocks, 256, 0, stream>>>((const float4*)x, Kws, (float4*)out, nq);
}

// Round 3
// 15.176 us; speedup vs baseline: 2.6655x; 1.1658x over previous
//
#include <hip/hip_runtime.h>
#include <math.h>

// ============================================================================
// Single fused kernel.
//
// logit(x0,x1) = u0^T K u1,  u0=[1,cos x0,sin x0], u1=[1,cos x1,sin x1],
// K folded with W[0] and b[0].
//
// Layer unitary = CP * D * S * P * HH * CNOT. CP,S,P diagonal; HH*CNOT is a
// constant real +-0.5 matrix. Per layer: L = D @ (e^{i th_i} * HHC) with CP
// scaling row 3, then U = L @ U. Wave 0 of each block computes this with
// shuffle-based 4x4 complex matmuls (lane t<16 owns element (i,j)), then
// A = Re(Dp^dag (U^dag Z U) Dp) goes to 16 floats of LDS; after one
// __syncthreads every thread folds W,b into private coefficients and streams.
// ============================================================================

// D_q = RY(phid) @ RZ(r) element [a][b]
__device__ inline void delem(float r, float phid, int a, int b,
                             float& outr, float& outi) {
    float sn, cs; __sincosf(0.5f * r, &sn, &cs);      // em = (cs,-sn), ep = (cs,+sn)
    float sd, cd; __sincosf(0.5f * phid, &sd, &cd);
    float f = (a == b) ? cd : ((a == 1) ? sd : -sd);  // RY magnitude
    outr = f * cs;
    outi = f * ((b == 1) ? sn : -sn);
}

// C = A @ B (complex 4x4), lane t = 4*i+j owns C[i][j]; wave-shuffle operands
__device__ inline void cmatmul_shfl(float Ar, float Ai, float Br, float Bi,
                                    int i, int j, float& Cr, float& Ci) {
    float cr = 0.f, ci = 0.f;
    #pragma unroll
    for (int k = 0; k < 4; ++k) {
        float ar = __shfl(Ar, 4 * i + k, 64);
        float ai = __shfl(Ai, 4 * i + k, 64);
        float br = __shfl(Br, 4 * k + j, 64);
        float bi = __shfl(Bi, 4 * k + j, 64);
        cr = fmaf(ar, br, fmaf(-ai, bi, cr));
        ci = fmaf(ar, bi, fmaf(ai, br, ci));
    }
    Cr = cr; Ci = ci;
}

__device__ inline float eval_sample(float x0, float x1,
                                    float k00, float k01, float k02,
                                    float k10, float k11, float k12,
                                    float k20, float k21, float k22) {
    float s0, c0, s1, c1;
    __sincosf(x0, &s0, &c0);
    __sincosf(x1, &s1, &c1);
    float e0 = fmaf(s1, k02, fmaf(c1, k01, k00));
    float e1 = fmaf(s1, k12, fmaf(c1, k11, k10));
    float e2 = fmaf(s1, k22, fmaf(c1, k21, k20));
    return fmaf(s0, e2, fmaf(c0, e1, e0));
}

__global__ __launch_bounds__(256) void fraud_fused(
        const float* __restrict__ params, int n_layers,
        const float* __restrict__ W, const float* __restrict__ bias,
        const float4* __restrict__ x, float4* __restrict__ out, int nquads) {
    __shared__ float Am[16];

    const int t = threadIdx.x;

    if (t < 64) {  // wave 0: compute A (lanes >=16 compute harmless duplicates)
        const int i = (t >> 2) & 3, j = t & 3;
        const int i0 = i >> 1, i1 = i & 1, j0 = j >> 1, j1 = j & 1;

        float Ur = (i == j) ? 1.f : 0.f, Ui = 0.f;

        for (int l = 0; l < n_layers; ++l) {
            float p[14];
            #pragma unroll
            for (int q = 0; q < 14; ++q) {
                float v = params[l * 14 + q];
                float lim = (q < 12) ? 5.0f : 1.0f;
                p[q] = fminf(fmaxf(v, -lim), lim);
            }

            // E[i][j] = e^{i th_i} * HHC[i][j];  HHC = HH with cols 2,3 swapped
            int sj = j ^ (j >> 1);
            float hh = (__popc(i & sj) & 1) ? -0.5f : 0.5f;
            float t0 = p[4] + p[6], t1 = p[5] + p[7];
            float th = p[2] * (float)i0 + p[3] * (float)i1
                     + 0.5f * t0 * (float)(2 * i0 - 1)
                     + 0.5f * t1 * (float)(2 * i1 - 1);
            float sth, cth; __sincosf(th, &sth, &cth);
            float Er = hh * cth, Ei = hh * sth;

            // D4[i][j] = D0[i0][j0] * D1[i1][j1]
            float ar, ai, br, bi;
            delem(p[8], p[10], i0, j0, ar, ai);
            delem(p[9], p[11], i1, j1, br, bi);
            float D4r = ar * br - ai * bi;
            float D4i = ar * bi + ai * br;

            // L = D4 @ E, CP scales row 3
            float Lr, Li;
            cmatmul_shfl(D4r, D4i, Er, Ei, i, j, Lr, Li);
            if (i == 3) {
                float cps, cpc; __sincosf(p[12] + p[13], &cps, &cpc);
                float nr = Lr * cpc - Li * cps;
                float ni = Lr * cps + Li * cpc;
                Lr = nr; Li = ni;
            }

            // U = L @ U
            if (l == 0) { Ur = Lr; Ui = Li; }
            else {
                float nr, ni;
                cmatmul_shfl(Lr, Li, Ur, Ui, i, j, nr, ni);
                Ur = nr; Ui = ni;
            }
        }

        // M[i][j] = sum_k z_k conj(U[k][i]) U[k][j]
        float mr = 0.f, mi = 0.f;
        #pragma unroll
        for (int k = 0; k < 4; ++k) {
            float z = (k < 2) ? 1.f : -1.f;
            float u1r =  __shfl(Ur, 4 * k + i, 64);
            float u1i = -__shfl(Ui, 4 * k + i, 64);
            float u2r =  __shfl(Ur, 4 * k + j, 64);
            float u2i =  __shfl(Ui, 4 * k + j, 64);
            mr += z * (u1r * u2r - u1i * u2i);
            mi += z * (u1r * u2i + u1i * u2r);
        }
        // A = Re(conj(dph_i) * M * dph_j), dph = (1, -i, -i, -1)
        float dri = (i == 0) ? 1.f : ((i == 3) ? -1.f : 0.f);
        float dii = (i == 0 || i == 3) ? 0.f : -1.f;
        float drj = (j == 0) ? 1.f : ((j == 3) ? -1.f : 0.f);
        float dij = (j == 0 || j == 3) ? 0.f : -1.f;
        float fr = dri * drj + dii * dij;
        float fi = dri * dij - dii * drj;
        if (t < 16) Am[t] = mr * fr - mi * fi;
    }
    __syncthreads();

    // every thread folds its private coefficients
    float A00 = Am[0],  A01 = Am[1],  A02 = Am[2],  A03 = Am[3];
    float A11 = Am[5],  A12 = Am[6],  A13 = Am[7];
    float A22 = Am[10], A23 = Am[11], A33 = Am[15];
    float w = W[0], bb = bias[0];
    float k00 = 0.25f * (A00 + A11 + A22 + A33) * w + bb;
    float k01 = 0.25f * (A00 - A11 + A22 - A33) * w;
    float k02 = 0.5f  * (A01 + A23) * w;
    float k10 = 0.25f * (A00 + A11 - A22 - A33) * w;
    float k11 = 0.25f * (A00 - A11 - A22 + A33) * w;
    float k12 = 0.5f  * (A01 - A23) * w;
    float k20 = 0.5f  * (A02 + A13) * w;
    float k21 = 0.5f  * (A02 - A13) * w;
    float k22 = 0.5f  * (A03 + A12) * w;

    const int gsize = gridDim.x * 256;
    for (int q = blockIdx.x * 256 + t; q < nquads; q += gsize) {
        float4 xa = x[2 * q];
        float4 xb = x[2 * q + 1];
        float4 o;
        o.x = eval_sample(xa.x, xa.y, k00, k01, k02, k10, k11, k12, k20, k21, k22);
        o.y = eval_sample(xa.z, xa.w, k00, k01, k02, k10, k11, k12, k20, k21, k22);
        o.z = eval_sample(xb.x, xb.y, k00, k01, k02, k10, k11, k12, k20, k21, k22);
        o.w = eval_sample(xb.z, xb.w, k00, k01, k02, k10, k11, k12, k20, k21, k22);
        out[q] = o;
    }
}

extern "C" void kernel_launch(void* const* d_in, const int* in_sizes, int n_in,
                              void* d_out, int out_size, void* d_ws, size_t ws_size,
                              hipStream_t stream) {
    const float* x      = (const float*)d_in[0];
    const float* params = (const float*)d_in[1];
    const float* W      = (const float*)d_in[2];
    const float* b      = (const float*)d_in[3];
    float* out = (float*)d_out;

    int n_layers = in_sizes[1] / 14;
    int B = out_size;              // n_classes == 1
    int nq = B / 4;                // B = 4194304, divisible by 4

    int blocks = 2048;             // 8 blocks/CU, full occupancy, grid-stride
    int maxb = (nq + 255) / 256;
    if (blocks > maxb) blocks = maxb;

    fraud_fused<<<blocks, 256, 0, stream>>>(params, n_layers, W, b,
                                            (const float4*)x, (float4*)out, nq);
}